// Round 14
// baseline (229.666 us; speedup 1.0000x reference)
//
#include <hip/hip_runtime.h>
#include <math.h>

#define BB   2
#define SS   1024
#define HH   768
#define DD   24
#define HIDD 96
#define VINN 2304   // 3*H
#define VHIDD 768
#define NRR  2048   // BB*SS

typedef __attribute__((ext_vector_type(8))) short short8;
typedef __attribute__((ext_vector_type(4))) float floatx4;

static __device__ inline unsigned short f2bf(float x) {
    unsigned int u = __float_as_uint(x);
    u = (u + 0x7FFFu + ((u >> 16) & 1u)) >> 16;
    return (unsigned short)u;
}
static __device__ inline unsigned int pack2(float a, float b) {
    return (unsigned int)f2bf(a) | ((unsigned int)f2bf(b) << 16);
}

// async global -> LDS, 16 B per lane; LDS dest = wave-uniform base + lane*16
static __device__ inline void gl16(const unsigned short* g, unsigned short* l) {
    __builtin_amdgcn_global_load_lds(
        (const __attribute__((address_space(1))) unsigned int*)g,
        (__attribute__((address_space(3))) unsigned int*)l,
        16, 0, 0);
}

// ---------------- Kernel 0: fused prep --------------------------------------
// blocks 0..63: Z projections (MFMA), packed-bf16 output.
// blocks 64..: f32->bf16 transpose-convert for Wv1T / Wv2T / HiT.
__global__ __launch_bounds__(256) void k_prep(
    const float* __restrict__ Hj, const float* __restrict__ Hi,
    const float* __restrict__ Wpj, const float* __restrict__ Wpi,
    const float* __restrict__ Wv1, const float* __restrict__ Wv2,
    unsigned* __restrict__ Zjp, unsigned* __restrict__ Zip,
    unsigned short* __restrict__ Wv1T, unsigned short* __restrict__ Wv2T,
    unsigned short* __restrict__ HiT)
{
    __shared__ __align__(16) unsigned short sAz[64][72];
    __shared__ __align__(16) unsigned short sBTz[32][72];
    __shared__ float tile[32][33];
    int bid = blockIdx.x;
    int tid = threadIdx.x;

    if (bid < 64) {
        // ---------------- zproj ----------------
        int w = tid >> 6, lane = tid & 63;
        int quad = lane >> 4, col = lane & 15;
        int m0 = bid * 64;
        bool isJ = (m0 < NRR);
        const float* src = isJ ? Hj : Hi;
        const float* Wp  = isJ ? Wpj : Wpi;
        unsigned* Zp     = isJ ? Zjp : Zip;
        int rowbase = isJ ? m0 : (m0 - NRR);

        floatx4 acc[2];
        acc[0] = (floatx4){0.f,0.f,0.f,0.f};
        acc[1] = (floatx4){0.f,0.f,0.f,0.f};

        for (int kb = 0; kb < HH; kb += 64) {
            #pragma unroll
            for (int i = 0; i < 4; ++i) {
                int f4 = tid + i*256;
                int r = f4 >> 4, c4 = f4 & 15;
                float4 v = *(const float4*)(src + (size_t)(rowbase + r)*HH + kb + c4*4);
                uint2 pkt; pkt.x = pack2(v.x, v.y); pkt.y = pack2(v.z, v.w);
                *(uint2*)&sAz[r][c4*4] = pkt;
            }
            {
                const float* wsrc = Wp + (size_t)kb*DD;
                #pragma unroll
                for (int i = 0; i < 6; ++i) {
                    int idx = tid + i*256;
                    int k = idx / DD, n = idx % DD;
                    sBTz[n][k] = f2bf(wsrc[idx]);
                }
            }
            __syncthreads();
            #pragma unroll
            for (int kt = 0; kt < 2; ++kt) {
                short8 av = *(const short8*)&sAz[w*16 + col][kt*32 + quad*8];
                #pragma unroll
                for (int nt = 0; nt < 2; ++nt) {
                    short8 bv = *(const short8*)&sBTz[nt*16 + col][kt*32 + quad*8];
                    acc[nt] = __builtin_amdgcn_mfma_f32_16x16x32_bf16(av, bv, acc[nt], 0, 0, 0);
                }
            }
            __syncthreads();
        }
        #pragma unroll
        for (int nt = 0; nt < 2; ++nt) {
            #pragma unroll
            for (int r = 0; r < 4; ++r) {
                float v = acc[nt][r];
                float vn = __shfl_xor(v, 1, 64);
                int n = nt*16 + col;
                if (!(col & 1) && n < DD) {
                    int m = w*16 + quad*4 + r;
                    Zp[(size_t)(rowbase + m)*12 + (n >> 1)] = pack2(v, vn);
                }
            }
        }
        return;
    }

    // ---------------- tconv segments ----------------
    int b2 = bid - 64;
    const float* in; unsigned short* out; int R, C, r0, c0;
    if (b2 < 1728) {                 // Wv1T: [2304][768] -> [768][2304]
        in = Wv1; out = Wv1T; R = VINN; C = VHIDD;
        c0 = (b2 % 24) * 32; r0 = (b2 / 24) * 32;
    } else if (b2 < 2304) {          // Wv2T: [768][768] -> [768][768]
        int t = b2 - 1728;
        in = Wv2; out = Wv2T; R = VHIDD; C = HH;
        c0 = (t % 24) * 32; r0 = (t / 24) * 32;
    } else {                          // HiT: per batch [1024][768] -> [768][1024]
        int t = b2 - 2304;
        int z = t / 768; t %= 768;
        in = Hi + (size_t)z*SS*HH; out = HiT + (size_t)z*HH*SS;
        R = SS; C = HH;
        c0 = (t % 24) * 32; r0 = (t / 24) * 32;
    }
    int tc = tid & 31, tr = tid >> 5;
    #pragma unroll
    for (int i = 0; i < 4; ++i)
        tile[tr + i*8][tc] = in[(size_t)(r0 + tr + i*8)*C + c0 + tc];
    __syncthreads();
    #pragma unroll
    for (int i = 0; i < 4; ++i)
        out[(size_t)(c0 + tr + i*8)*R + r0 + tc] = f2bf(tile[tc][tr + i*8]);
}

// ---------------- Kernel 2: MFMA logits + softmax -> probs (bf16) ----------
// TC=64 chunks, double-buffered (23 KB LDS).
#define LSTR 72
#define TC 64
__global__ __launch_bounds__(256) void k_attn(
    const unsigned* __restrict__ Zjp, const unsigned* __restrict__ Zip,
    const float* __restrict__ W1, const float* __restrict__ b1,
    const float* __restrict__ W2,
    const float* __restrict__ mask, unsigned short* __restrict__ probs)
{
    int row = blockIdx.x;       // b*S + s
    int b = row >> 10;
    int tid = threadIdx.x;
    int lane = tid & 63, wv = tid >> 6;
    int quad = lane >> 4, col = lane & 15;

    __shared__ __align__(16) unsigned short sAB[2][TC*LSTR]; // B-build flat, then A dbuf
    __shared__ __align__(16) float sLog[SS];
    __shared__ unsigned sZjp[12];
    __shared__ float sW2[HIDD];
    __shared__ float sRed[4];
    unsigned short* sABf = &sAB[0][0];   // flat view (rows 0..127)

    if (tid < 12) sZjp[tid] = Zjp[(size_t)row*12 + tid];
    if (tid < HIDD) sW2[tid] = W2[tid];
    __syncthreads();

    // ---- build B flat (rows h = 0..95, k = 0..63) ----
    if (tid < HIDD) {
        int h = tid;
        float zj[24];
        #pragma unroll
        for (int u = 0; u < 12; ++u) {
            unsigned z = sZjp[u];
            zj[2*u]   = __uint_as_float(z << 16);
            zj[2*u+1] = __uint_as_float(z & 0xffff0000u);
        }
        float tj = b1[h];
        #pragma unroll
        for (int d = 0; d < DD; ++d) tj = fmaf(zj[d], W1[d*HIDD + h], tj);
        unsigned short* rowp = sABf + h*LSTR;
        #pragma unroll
        for (int d = 0; d < DD; ++d)
            rowp[d] = f2bf(fmaf(zj[d], W1[(48+d)*HIDD + h], W1[(24+d)*HIDD + h]));
        #pragma unroll
        for (int d = 0; d < DD; ++d)
            rowp[24+d] = f2bf(W1[(72+d)*HIDD + h]);
        rowp[48] = f2bf(tj);
        #pragma unroll
        for (int k = 49; k < 64; ++k) rowp[k] = 0;
    }
    __syncthreads();

    // hoist B fragments (h-side, MFMA A-operand) + per-lane w2 coeffs
    short8 bfr[6][2];
    #pragma unroll
    for (int nf = 0; nf < 6; ++nf)
        #pragma unroll
        for (int kt = 0; kt < 2; ++kt)
            bfr[nf][kt] = *(const short8*)&sABf[(nf*16 + col)*LSTR + kt*32 + quad*8];
    float4 w2q[6];
    #pragma unroll
    for (int nf = 0; nf < 6; ++nf)
        w2q[nf] = *(const float4*)&sW2[nf*16 + quad*4];
    __syncthreads();   // sAB now reused as A double-buffer

    // constant region k=48..63, both buffers (written once)
    if (tid < 128) {
        int bf = tid >> 6, r = tid & 63;
        unsigned short* rowp = &sAB[bf][r*LSTR];
        uint4 w0; w0.x = 0x3F80u; w0.y = 0; w0.z = 0; w0.w = 0;
        *(uint4*)&rowp[48] = w0;
        uint4 zz; zz.x = 0; zz.y = 0; zz.z = 0; zz.w = 0;
        *(uint4*)&rowp[56] = zz;
    }

    int t_loc = tid >> 2, ss = tid & 3;
    const unsigned* zbase = Zip + (size_t)(b << 10) * 12;

    // hoist Zj unpack (chunk-invariant) for this thread's 3 q-uints
    float zalo[3], zahi[3];
    #pragma unroll
    for (int u = 0; u < 3; ++u) {
        unsigned za = sZjp[3*ss + u];
        zalo[u] = __uint_as_float(za << 16);
        zahi[u] = __uint_as_float(za & 0xffff0000u);
    }

    // A-pack for one chunk (4 threads per t-row; each does 3 q-uints)
    auto pack = [&](int chunk, int bf) {
        int t = chunk*TC + t_loc;
        const unsigned* zr = zbase + (size_t)t*12;
        unsigned short* rowp = &sAB[bf][t_loc*LSTR];
        if (ss < 3) {
            uint4 cp = *(const uint4*)(zr + 4*ss);
            *(uint4*)&rowp[8*ss] = cp;
        }
        unsigned myz[3];
        #pragma unroll
        for (int u = 0; u < 3; ++u) myz[u] = zr[3*ss + u];
        #pragma unroll
        for (int u = 0; u < 3; ++u) {
            unsigned zb = myz[u];
            float blo = __uint_as_float(zb << 16);
            float bhi = __uint_as_float(zb & 0xffff0000u);
            unsigned dlo = __float_as_uint(fabsf(zalo[u] - blo)) + 0x8000u;
            unsigned dhi = __float_as_uint(fabsf(zahi[u] - bhi)) + 0x8000u;
            *(unsigned*)&rowp[24 + 6*ss + 2*u] =
                __builtin_amdgcn_perm(dhi, dlo, 0x07060302u);
        }
    };

    pack(0, 0);
    __syncthreads();

    for (int chunk = 0; chunk < SS/TC; ++chunk) {
        int cur = chunk & 1;
        if (chunk + 1 < SS/TC) pack(chunk + 1, cur ^ 1);

        // MFMA: D[h][t]; per-lane fold over (hf, reg), cross-quad reduce
        int arow = wv*16 + col;
        short8 av0 = *(const short8*)&sAB[cur][arow*LSTR + quad*8];
        short8 av1 = *(const short8*)&sAB[cur][arow*LSTR + 32 + quad*8];
        float s0 = 0.f;
        #pragma unroll
        for (int hf = 0; hf < 6; ++hf) {
            floatx4 a0 = {0.f,0.f,0.f,0.f};
            a0 = __builtin_amdgcn_mfma_f32_16x16x32_bf16(bfr[hf][0], av0, a0, 0, 0, 0);
            a0 = __builtin_amdgcn_mfma_f32_16x16x32_bf16(bfr[hf][1], av1, a0, 0, 0, 0);
            float w2v[4] = {w2q[hf].x, w2q[hf].y, w2q[hf].z, w2q[hf].w};
            #pragma unroll
            for (int r = 0; r < 4; ++r)
                s0 = fmaf(fmaxf(a0[r], 0.f), w2v[r], s0);
        }
        s0 += __shfl_xor(s0, 16, 64);
        s0 += __shfl_xor(s0, 32, 64);
        if (lane < 16)
            sLog[chunk*TC + wv*16 + lane] = s0;
        __syncthreads();
    }

    // ---- softmax ----
    float lv[4];
    #pragma unroll
    for (int i = 0; i < 4; ++i) {
        int t = tid + i*256;
        lv[i] = sLog[t] + (1.0f - mask[(size_t)(b<<10) + t]) * (-3.402823466e+38f);
    }
    float m = fmaxf(fmaxf(lv[0], lv[1]), fmaxf(lv[2], lv[3]));
    #pragma unroll
    for (int off = 32; off; off >>= 1) m = fmaxf(m, __shfl_down(m, off, 64));
    if (lane == 0) sRed[wv] = m;
    __syncthreads();
    float M = fmaxf(fmaxf(sRed[0], sRed[1]), fmaxf(sRed[2], sRed[3]));
    float e[4]; float ssum = 0.f;
    #pragma unroll
    for (int i = 0; i < 4; ++i) { e[i] = expf(lv[i] - M); ssum += e[i]; }
    #pragma unroll
    for (int off = 32; off; off >>= 1) ssum += __shfl_down(ssum, off, 64);
    __syncthreads();
    if (lane == 0) sRed[wv] = ssum;
    __syncthreads();
    float inv = 1.0f / (sRed[0] + sRed[1] + sRed[2] + sRed[3]);
    #pragma unroll
    for (int i = 0; i < 4; ++i)
        probs[(size_t)row*SS + tid + i*256] = f2bf(e[i] * inv);
}

// ---------------- Kernel 3: no-split GEMM, 64Mx32N, BK=128, fused epi ------
// MODE 0: msgin builder (ctx | hj | ctx*hj, bf16)
// MODE 1: Y1 = bf16(relu(acc + bias))
// MODE 2: out = f32(alpha*(acc + bias))
template<int MODE>
__global__ __launch_bounds__(256) void k_mgemm_nf(
    const unsigned short* __restrict__ A,
    const unsigned short* __restrict__ BT,
    const float* __restrict__ bias,
    const float* __restrict__ Hj,
    const float* __restrict__ alpha_p,
    void* __restrict__ Cout,
    int K, int bt_bstride)
{
    __shared__ __align__(16) unsigned short sA[64*128];   // 16 KB
    __shared__ __align__(16) unsigned short sB[32*128];   //  8 KB
    int tid = threadIdx.x;
    int w = tid >> 6, lane = tid & 63;
    int quad = lane >> 4, col = lane & 15;

    int n0 = blockIdx.x * 32, m0 = blockIdx.y * 64;
    int nk = K >> 7;                 // BK=128
    const unsigned short* Bb = BT + (size_t)(m0 >> 10) * bt_bstride;

    // gl16 with 128-ushort rows: one instruction covers 4 rows
    int srow = lane >> 4;            // 0..3
    int skc  = (lane & 15) * 8;      // ushort offset within row

    floatx4 acc[2];
    acc[0] = (floatx4){0.f,0.f,0.f,0.f};
    acc[1] = (floatx4){0.f,0.f,0.f,0.f};

    for (int kb = 0; kb < nk; ++kb) {
        int kofs = kb*128;
        #pragma unroll
        for (int i = 0; i < 4; ++i) {    // A rows w*16 .. w*16+15
            int rbase = w*16 + i*4;
            gl16(A + (size_t)(m0 + rbase + srow)*K + kofs + skc, &sA[rbase*128]);
        }
        #pragma unroll
        for (int i = 0; i < 2; ++i) {    // B rows w*8 .. w*8+7
            int rbase = w*8 + i*4;
            gl16(Bb + (size_t)(n0 + rbase + srow)*K + kofs + skc, &sB[rbase*128]);
        }
        __syncthreads();
        #pragma unroll
        for (int kt = 0; kt < 4; ++kt) {
            short8 av = *(const short8*)&sA[(w*16 + col)*128 + kt*32 + quad*8];
            #pragma unroll
            for (int nf = 0; nf < 2; ++nf) {
                short8 bv = *(const short8*)&sB[(nf*16 + col)*128 + kt*32 + quad*8];
                acc[nf] = __builtin_amdgcn_mfma_f32_16x16x32_bf16(av, bv, acc[nf], 0, 0, 0);
            }
        }
        __syncthreads();
    }

    float alpha = (MODE == 2) ? alpha_p[0] : 1.0f;
    #pragma unroll
    for (int nf = 0; nf < 2; ++nf) {
        int n = n0 + nf*16 + col;
        #pragma unroll
        for (int r = 0; r < 4; ++r) {
            int m = w*16 + quad*4 + r;
            size_t g = (size_t)(m0 + m);
            float v = acc[nf][r];
            if (MODE == 0) {
                float hj = Hj[g*HH + n];
                unsigned short* msgin = (unsigned short*)Cout;
                msgin[g*VINN + n]        = f2bf(v);
                msgin[g*VINN + HH + n]   = f2bf(hj);
                msgin[g*VINN + 2*HH + n] = f2bf(v*hj);
            } else if (MODE == 1) {
                ((unsigned short*)Cout)[g*VHIDD + n] =
                    f2bf(fmaxf(v + bias[n], 0.f));
            } else {
                ((float*)Cout)[g*HH + n] = alpha*(v + bias[n]);
            }
        }
    }
}

extern "C" void kernel_launch(void* const* d_in, const int* in_sizes, int n_in,
                              void* d_out, int out_size, void* d_ws, size_t ws_size,
                              hipStream_t stream)
{
    const float* Hj   = (const float*)d_in[0];
    const float* Hi   = (const float*)d_in[1];
    const float* mask = (const float*)d_in[2];
    const float* Wpj  = (const float*)d_in[3];
    const float* Wpi  = (const float*)d_in[4];
    const float* W1   = (const float*)d_in[5];
    const float* b1   = (const float*)d_in[6];
    const float* W2   = (const float*)d_in[7];
    const float* Wv1  = (const float*)d_in[9];
    const float* bv1  = (const float*)d_in[10];
    const float* Wv2  = (const float*)d_in[11];
    const float* bv2  = (const float*)d_in[12];
    const float* alpha = (const float*)d_in[13];
    float* out = (float*)d_out;

    const int NR = NRR;                   // 2048
    char* p = (char*)d_ws;
    auto alloc = [&](size_t bytes) {
        char* r = p; p += (bytes + 255) & ~(size_t)255; return r;
    };
    unsigned* Zjp          = (unsigned*)alloc((size_t)NR*12*4);
    unsigned* Zip          = (unsigned*)alloc((size_t)NR*12*4);
    unsigned short* probsb = (unsigned short*)alloc((size_t)NR*SS*2);
    unsigned short* HiT    = (unsigned short*)alloc((size_t)BB*HH*SS*2);
    unsigned short* Wv1T   = (unsigned short*)alloc((size_t)VHIDD*VINN*2);
    unsigned short* Wv2T   = (unsigned short*)alloc((size_t)HH*VHIDD*2);
    unsigned short* msginb = (unsigned short*)alloc((size_t)NR*VINN*2);
    unsigned short* Y1b    = (unsigned short*)alloc((size_t)NR*VHIDD*2);

    // prep: 64 zproj blocks + 1728 (Wv1T) + 576 (Wv2T) + 1536 (HiT) tconv blocks
    k_prep<<<64 + 1728 + 576 + 1536, 256, 0, stream>>>(
        Hj, Hi, Wpj, Wpi, Wv1, Wv2, Zjp, Zip, Wv1T, Wv2T, HiT);

    k_attn<<<NR, 256, 0, stream>>>(Zjp, Zip, W1, b1, W2, mask, probsb);

    // ctx GEMM: M=2048 (batch via bt stride), N=768, K=1024, BK=128,
    // fused msgin epilogue. 24 x 32 = 768 blocks.
    k_mgemm_nf<0><<<dim3(HH/32, NR/64), 256, 0, stream>>>(
        probsb, HiT, nullptr, Hj, alpha, msginb, SS, HH*SS);

    // MLP GEMM1: K=2304, BK=128, fused bias+relu epilogue. 768 blocks.
    k_mgemm_nf<1><<<dim3(VHIDD/32, NR/64), 256, 0, stream>>>(
        msginb, Wv1T, bv1, nullptr, alpha, Y1b, VINN, 0);

    // MLP GEMM2: K=768, BK=128, fused f32 epilogue. 768 blocks.
    k_mgemm_nf<2><<<dim3(HH/32, NR/64), 256, 0, stream>>>(
        Y1b, Wv2T, bv2, nullptr, alpha, out, VHIDD, 0);
}

// Round 15
// 203.234 us; speedup vs baseline: 1.1301x; 1.1301x over previous
//
#include <hip/hip_runtime.h>
#include <math.h>

#define BB   2
#define SS   1024
#define HH   768
#define DD   24
#define HIDD 96
#define VINN 2304   // 3*H
#define VHIDD 768
#define NRR  2048   // BB*SS

typedef __attribute__((ext_vector_type(8))) short short8;
typedef __attribute__((ext_vector_type(4))) float floatx4;

static __device__ inline unsigned short f2bf(float x) {
    unsigned int u = __float_as_uint(x);
    u = (u + 0x7FFFu + ((u >> 16) & 1u)) >> 16;
    return (unsigned short)u;
}
static __device__ inline unsigned int pack2(float a, float b) {
    return (unsigned int)f2bf(a) | ((unsigned int)f2bf(b) << 16);
}

// async global -> LDS, 16 B per lane; LDS dest = wave-uniform base + lane*16
static __device__ inline void gl16(const unsigned short* g, unsigned short* l) {
    __builtin_amdgcn_global_load_lds(
        (const __attribute__((address_space(1))) unsigned int*)g,
        (__attribute__((address_space(3))) unsigned int*)l,
        16, 0, 0);
}

// ---------------- Kernel 0: fused prep --------------------------------------
// blocks 0..63: Z projections (MFMA), packed-bf16 output.
// blocks 64..: f32->bf16 transpose-convert for Wv1T / Wv2T / HiT.
__global__ __launch_bounds__(256) void k_prep(
    const float* __restrict__ Hj, const float* __restrict__ Hi,
    const float* __restrict__ Wpj, const float* __restrict__ Wpi,
    const float* __restrict__ Wv1, const float* __restrict__ Wv2,
    unsigned* __restrict__ Zjp, unsigned* __restrict__ Zip,
    unsigned short* __restrict__ Wv1T, unsigned short* __restrict__ Wv2T,
    unsigned short* __restrict__ HiT)
{
    __shared__ __align__(16) unsigned short sAz[64][72];
    __shared__ __align__(16) unsigned short sBTz[32][72];
    __shared__ float tile[32][33];
    int bid = blockIdx.x;
    int tid = threadIdx.x;

    if (bid < 64) {
        // ---------------- zproj ----------------
        int w = tid >> 6, lane = tid & 63;
        int quad = lane >> 4, col = lane & 15;
        int m0 = bid * 64;
        bool isJ = (m0 < NRR);
        const float* src = isJ ? Hj : Hi;
        const float* Wp  = isJ ? Wpj : Wpi;
        unsigned* Zp     = isJ ? Zjp : Zip;
        int rowbase = isJ ? m0 : (m0 - NRR);

        floatx4 acc[2];
        acc[0] = (floatx4){0.f,0.f,0.f,0.f};
        acc[1] = (floatx4){0.f,0.f,0.f,0.f};

        for (int kb = 0; kb < HH; kb += 64) {
            #pragma unroll
            for (int i = 0; i < 4; ++i) {
                int f4 = tid + i*256;
                int r = f4 >> 4, c4 = f4 & 15;
                float4 v = *(const float4*)(src + (size_t)(rowbase + r)*HH + kb + c4*4);
                uint2 pkt; pkt.x = pack2(v.x, v.y); pkt.y = pack2(v.z, v.w);
                *(uint2*)&sAz[r][c4*4] = pkt;
            }
            {
                const float* wsrc = Wp + (size_t)kb*DD;
                #pragma unroll
                for (int i = 0; i < 6; ++i) {
                    int idx = tid + i*256;
                    int k = idx / DD, n = idx % DD;
                    sBTz[n][k] = f2bf(wsrc[idx]);
                }
            }
            __syncthreads();
            #pragma unroll
            for (int kt = 0; kt < 2; ++kt) {
                short8 av = *(const short8*)&sAz[w*16 + col][kt*32 + quad*8];
                #pragma unroll
                for (int nt = 0; nt < 2; ++nt) {
                    short8 bv = *(const short8*)&sBTz[nt*16 + col][kt*32 + quad*8];
                    acc[nt] = __builtin_amdgcn_mfma_f32_16x16x32_bf16(av, bv, acc[nt], 0, 0, 0);
                }
            }
            __syncthreads();
        }
        #pragma unroll
        for (int nt = 0; nt < 2; ++nt) {
            #pragma unroll
            for (int r = 0; r < 4; ++r) {
                float v = acc[nt][r];
                float vn = __shfl_xor(v, 1, 64);
                int n = nt*16 + col;
                if (!(col & 1) && n < DD) {
                    int m = w*16 + quad*4 + r;
                    Zp[(size_t)(rowbase + m)*12 + (n >> 1)] = pack2(v, vn);
                }
            }
        }
        return;
    }

    // ---------------- tconv segments ----------------
    int b2 = bid - 64;
    const float* in; unsigned short* out; int R, C, r0, c0;
    if (b2 < 1728) {                 // Wv1T: [2304][768] -> [768][2304]
        in = Wv1; out = Wv1T; R = VINN; C = VHIDD;
        c0 = (b2 % 24) * 32; r0 = (b2 / 24) * 32;
    } else if (b2 < 2304) {          // Wv2T: [768][768] -> [768][768]
        int t = b2 - 1728;
        in = Wv2; out = Wv2T; R = VHIDD; C = HH;
        c0 = (t % 24) * 32; r0 = (t / 24) * 32;
    } else {                          // HiT: per batch [1024][768] -> [768][1024]
        int t = b2 - 2304;
        int z = t / 768; t %= 768;
        in = Hi + (size_t)z*SS*HH; out = HiT + (size_t)z*HH*SS;
        R = SS; C = HH;
        c0 = (t % 24) * 32; r0 = (t / 24) * 32;
    }
    int tc = tid & 31, tr = tid >> 5;
    #pragma unroll
    for (int i = 0; i < 4; ++i)
        tile[tr + i*8][tc] = in[(size_t)(r0 + tr + i*8)*C + c0 + tc];
    __syncthreads();
    #pragma unroll
    for (int i = 0; i < 4; ++i)
        out[(size_t)(c0 + tr + i*8)*R + r0 + tc] = f2bf(tile[tc][tr + i*8]);
}

// ---------------- Kernel 2: MFMA logits + softmax -> probs (bf16) ----------
// TC=64 chunks, double-buffered (23 KB LDS).
#define LSTR 72
#define TC 64
__global__ __launch_bounds__(256) void k_attn(
    const unsigned* __restrict__ Zjp, const unsigned* __restrict__ Zip,
    const float* __restrict__ W1, const float* __restrict__ b1,
    const float* __restrict__ W2,
    const float* __restrict__ mask, unsigned short* __restrict__ probs)
{
    int row = blockIdx.x;       // b*S + s
    int b = row >> 10;
    int tid = threadIdx.x;
    int lane = tid & 63, wv = tid >> 6;
    int quad = lane >> 4, col = lane & 15;

    __shared__ __align__(16) unsigned short sAB[2][TC*LSTR]; // B-build flat, then A dbuf
    __shared__ __align__(16) float sLog[SS];
    __shared__ unsigned sZjp[12];
    __shared__ float sW2[HIDD];
    __shared__ float sRed[4];
    unsigned short* sABf = &sAB[0][0];   // flat view (rows 0..127)

    if (tid < 12) sZjp[tid] = Zjp[(size_t)row*12 + tid];
    if (tid < HIDD) sW2[tid] = W2[tid];
    __syncthreads();

    // ---- build B flat (rows h = 0..95, k = 0..63) ----
    if (tid < HIDD) {
        int h = tid;
        float zj[24];
        #pragma unroll
        for (int u = 0; u < 12; ++u) {
            unsigned z = sZjp[u];
            zj[2*u]   = __uint_as_float(z << 16);
            zj[2*u+1] = __uint_as_float(z & 0xffff0000u);
        }
        float tj = b1[h];
        #pragma unroll
        for (int d = 0; d < DD; ++d) tj = fmaf(zj[d], W1[d*HIDD + h], tj);
        unsigned short* rowp = sABf + h*LSTR;
        #pragma unroll
        for (int d = 0; d < DD; ++d)
            rowp[d] = f2bf(fmaf(zj[d], W1[(48+d)*HIDD + h], W1[(24+d)*HIDD + h]));
        #pragma unroll
        for (int d = 0; d < DD; ++d)
            rowp[24+d] = f2bf(W1[(72+d)*HIDD + h]);
        rowp[48] = f2bf(tj);
        #pragma unroll
        for (int k = 49; k < 64; ++k) rowp[k] = 0;
    }
    __syncthreads();

    // hoist B fragments (h-side, MFMA A-operand) + per-lane w2 coeffs
    short8 bfr[6][2];
    #pragma unroll
    for (int nf = 0; nf < 6; ++nf)
        #pragma unroll
        for (int kt = 0; kt < 2; ++kt)
            bfr[nf][kt] = *(const short8*)&sABf[(nf*16 + col)*LSTR + kt*32 + quad*8];
    float4 w2q[6];
    #pragma unroll
    for (int nf = 0; nf < 6; ++nf)
        w2q[nf] = *(const float4*)&sW2[nf*16 + quad*4];
    __syncthreads();   // sAB now reused as A double-buffer

    // constant region k=48..63, both buffers (written once)
    if (tid < 128) {
        int bf = tid >> 6, r = tid & 63;
        unsigned short* rowp = &sAB[bf][r*LSTR];
        uint4 w0; w0.x = 0x3F80u; w0.y = 0; w0.z = 0; w0.w = 0;
        *(uint4*)&rowp[48] = w0;
        uint4 zz; zz.x = 0; zz.y = 0; zz.z = 0; zz.w = 0;
        *(uint4*)&rowp[56] = zz;
    }

    int t_loc = tid >> 2, ss = tid & 3;
    const unsigned* zbase = Zip + (size_t)(b << 10) * 12;

    // hoist Zj unpack (chunk-invariant) for this thread's 3 q-uints
    float zalo[3], zahi[3];
    #pragma unroll
    for (int u = 0; u < 3; ++u) {
        unsigned za = sZjp[3*ss + u];
        zalo[u] = __uint_as_float(za << 16);
        zahi[u] = __uint_as_float(za & 0xffff0000u);
    }

    // A-pack for one chunk (4 threads per t-row; each does 3 q-uints)
    auto pack = [&](int chunk, int bf) {
        int t = chunk*TC + t_loc;
        const unsigned* zr = zbase + (size_t)t*12;
        unsigned short* rowp = &sAB[bf][t_loc*LSTR];
        if (ss < 3) {
            uint4 cp = *(const uint4*)(zr + 4*ss);
            *(uint4*)&rowp[8*ss] = cp;
        }
        unsigned myz[3];
        #pragma unroll
        for (int u = 0; u < 3; ++u) myz[u] = zr[3*ss + u];
        #pragma unroll
        for (int u = 0; u < 3; ++u) {
            unsigned zb = myz[u];
            float blo = __uint_as_float(zb << 16);
            float bhi = __uint_as_float(zb & 0xffff0000u);
            unsigned dlo = __float_as_uint(fabsf(zalo[u] - blo)) + 0x8000u;
            unsigned dhi = __float_as_uint(fabsf(zahi[u] - bhi)) + 0x8000u;
            *(unsigned*)&rowp[24 + 6*ss + 2*u] =
                __builtin_amdgcn_perm(dhi, dlo, 0x07060302u);
        }
    };

    pack(0, 0);
    __syncthreads();

    for (int chunk = 0; chunk < SS/TC; ++chunk) {
        int cur = chunk & 1;
        if (chunk + 1 < SS/TC) pack(chunk + 1, cur ^ 1);

        // MFMA: D[h][t]; per-lane fold over (hf, reg), cross-quad reduce
        int arow = wv*16 + col;
        short8 av0 = *(const short8*)&sAB[cur][arow*LSTR + quad*8];
        short8 av1 = *(const short8*)&sAB[cur][arow*LSTR + 32 + quad*8];
        float s0 = 0.f;
        #pragma unroll
        for (int hf = 0; hf < 6; ++hf) {
            floatx4 a0 = {0.f,0.f,0.f,0.f};
            a0 = __builtin_amdgcn_mfma_f32_16x16x32_bf16(bfr[hf][0], av0, a0, 0, 0, 0);
            a0 = __builtin_amdgcn_mfma_f32_16x16x32_bf16(bfr[hf][1], av1, a0, 0, 0, 0);
            float w2v[4] = {w2q[hf].x, w2q[hf].y, w2q[hf].z, w2q[hf].w};
            #pragma unroll
            for (int r = 0; r < 4; ++r)
                s0 = fmaf(fmaxf(a0[r], 0.f), w2v[r], s0);
        }
        s0 += __shfl_xor(s0, 16, 64);
        s0 += __shfl_xor(s0, 32, 64);
        if (lane < 16)
            sLog[chunk*TC + wv*16 + lane] = s0;
        __syncthreads();
    }

    // ---- softmax ----
    float lv[4];
    #pragma unroll
    for (int i = 0; i < 4; ++i) {
        int t = tid + i*256;
        lv[i] = sLog[t] + (1.0f - mask[(size_t)(b<<10) + t]) * (-3.402823466e+38f);
    }
    float m = fmaxf(fmaxf(lv[0], lv[1]), fmaxf(lv[2], lv[3]));
    #pragma unroll
    for (int off = 32; off; off >>= 1) m = fmaxf(m, __shfl_down(m, off, 64));
    if (lane == 0) sRed[wv] = m;
    __syncthreads();
    float M = fmaxf(fmaxf(sRed[0], sRed[1]), fmaxf(sRed[2], sRed[3]));
    float e[4]; float ssum = 0.f;
    #pragma unroll
    for (int i = 0; i < 4; ++i) { e[i] = expf(lv[i] - M); ssum += e[i]; }
    #pragma unroll
    for (int off = 32; off; off >>= 1) ssum += __shfl_down(ssum, off, 64);
    __syncthreads();
    if (lane == 0) sRed[wv] = ssum;
    __syncthreads();
    float inv = 1.0f / (sRed[0] + sRed[1] + sRed[2] + sRed[3]);
    #pragma unroll
    for (int i = 0; i < 4; ++i)
        probs[(size_t)row*SS + tid + i*256] = f2bf(e[i] * inv);
}

// ---------------- Kernel 3: no-split GEMM, 64Mx32N, BK=64, gl16 dbuf -------
// One barrier per K-iteration: stage(k+1) -> compute(k) -> barrier.
// MODE 0: msgin builder (ctx | hj | ctx*hj, bf16)
// MODE 1: Y1 = bf16(relu(acc + bias))
// MODE 2: out = f32(alpha*(acc + bias))
template<int MODE>
__global__ __launch_bounds__(256) void k_mgemm_nf(
    const unsigned short* __restrict__ A,
    const unsigned short* __restrict__ BT,
    const float* __restrict__ bias,
    const float* __restrict__ Hj,
    const float* __restrict__ alpha_p,
    void* __restrict__ Cout,
    int K, int bt_bstride)
{
    __shared__ __align__(16) unsigned short sA[2][64*64];   // 2 x 8 KB
    __shared__ __align__(16) unsigned short sB[2][32*64];   // 2 x 4 KB
    int tid = threadIdx.x;
    int w = tid >> 6, lane = tid & 63;
    int quad = lane >> 4, col = lane & 15;

    int n0 = blockIdx.x * 32, m0 = blockIdx.y * 64;
    int nk = K >> 6;
    const unsigned short* Bb = BT + (size_t)(m0 >> 10) * bt_bstride;

    int srow = lane >> 3;            // 0..7
    int skc  = (lane & 7) * 8;       // ushort offset within row

    floatx4 acc[2];
    acc[0] = (floatx4){0.f,0.f,0.f,0.f};
    acc[1] = (floatx4){0.f,0.f,0.f,0.f};

    auto stage = [&](int kb, int bf) {
        int kofs = kb*64;
        gl16(A  + (size_t)(m0 + w*16     + srow)*K + kofs + skc, &sA[bf][(w*16)*64]);
        gl16(A  + (size_t)(m0 + w*16 + 8 + srow)*K + kofs + skc, &sA[bf][(w*16 + 8)*64]);
        gl16(Bb + (size_t)(n0 + w*8      + srow)*K + kofs + skc, &sB[bf][(w*8)*64]);
    };

    stage(0, 0);
    __syncthreads();

    for (int kb = 0; kb < nk; ++kb) {
        int cur = kb & 1;
        if (kb + 1 < nk) stage(kb + 1, cur ^ 1);
        #pragma unroll
        for (int kt = 0; kt < 2; ++kt) {
            short8 av = *(const short8*)&sA[cur][(w*16 + col)*64 + kt*32 + quad*8];
            #pragma unroll
            for (int nf = 0; nf < 2; ++nf) {
                short8 bv = *(const short8*)&sB[cur][(nf*16 + col)*64 + kt*32 + quad*8];
                acc[nf] = __builtin_amdgcn_mfma_f32_16x16x32_bf16(av, bv, acc[nf], 0, 0, 0);
            }
        }
        __syncthreads();   // drains next-tile gl16 (overlapped with MFMA) + joins waves
    }

    float alpha = (MODE == 2) ? alpha_p[0] : 1.0f;
    #pragma unroll
    for (int nf = 0; nf < 2; ++nf) {
        int n = n0 + nf*16 + col;
        #pragma unroll
        for (int r = 0; r < 4; ++r) {
            int m = w*16 + quad*4 + r;
            size_t g = (size_t)(m0 + m);
            float v = acc[nf][r];
            if (MODE == 0) {
                float hj = Hj[g*HH + n];
                unsigned short* msgin = (unsigned short*)Cout;
                msgin[g*VINN + n]        = f2bf(v);
                msgin[g*VINN + HH + n]   = f2bf(hj);
                msgin[g*VINN + 2*HH + n] = f2bf(v*hj);
            } else if (MODE == 1) {
                ((unsigned short*)Cout)[g*VHIDD + n] =
                    f2bf(fmaxf(v + bias[n], 0.f));
            } else {
                ((float*)Cout)[g*HH + n] = alpha*(v + bias[n]);
            }
        }
    }
}

extern "C" void kernel_launch(void* const* d_in, const int* in_sizes, int n_in,
                              void* d_out, int out_size, void* d_ws, size_t ws_size,
                              hipStream_t stream)
{
    const float* Hj   = (const float*)d_in[0];
    const float* Hi   = (const float*)d_in[1];
    const float* mask = (const float*)d_in[2];
    const float* Wpj  = (const float*)d_in[3];
    const float* Wpi  = (const float*)d_in[4];
    const float* W1   = (const float*)d_in[5];
    const float* b1   = (const float*)d_in[6];
    const float* W2   = (const float*)d_in[7];
    const float* Wv1  = (const float*)d_in[9];
    const float* bv1  = (const float*)d_in[10];
    const float* Wv2  = (const float*)d_in[11];
    const float* bv2  = (const float*)d_in[12];
    const float* alpha = (const float*)d_in[13];
    float* out = (float*)d_out;

    const int NR = NRR;                   // 2048
    char* p = (char*)d_ws;
    auto alloc = [&](size_t bytes) {
        char* r = p; p += (bytes + 255) & ~(size_t)255; return r;
    };
    unsigned* Zjp          = (unsigned*)alloc((size_t)NR*12*4);
    unsigned* Zip          = (unsigned*)alloc((size_t)NR*12*4);
    unsigned short* probsb = (unsigned short*)alloc((size_t)NR*SS*2);
    unsigned short* HiT    = (unsigned short*)alloc((size_t)BB*HH*SS*2);
    unsigned short* Wv1T   = (unsigned short*)alloc((size_t)VHIDD*VINN*2);
    unsigned short* Wv2T   = (unsigned short*)alloc((size_t)HH*VHIDD*2);
    unsigned short* msginb = (unsigned short*)alloc((size_t)NR*VINN*2);
    unsigned short* Y1b    = (unsigned short*)alloc((size_t)NR*VHIDD*2);

    // prep: 64 zproj blocks + 1728 (Wv1T) + 576 (Wv2T) + 1536 (HiT) tconv blocks
    k_prep<<<64 + 1728 + 576 + 1536, 256, 0, stream>>>(
        Hj, Hi, Wpj, Wpi, Wv1, Wv2, Zjp, Zip, Wv1T, Wv2T, HiT);

    k_attn<<<NR, 256, 0, stream>>>(Zjp, Zip, W1, b1, W2, mask, probsb);

    // ctx GEMM: M=2048 (batch via bt stride), N=768, K=1024, BK=64 dbuf,
    // fused msgin epilogue. 24 x 32 = 768 blocks.
    k_mgemm_nf<0><<<dim3(HH/32, NR/64), 256, 0, stream>>>(
        probsb, HiT, nullptr, Hj, alpha, msginb, SS, HH*SS);

    // MLP GEMM1: K=2304, BK=64 dbuf, fused bias+relu epilogue. 768 blocks.
    k_mgemm_nf<1><<<dim3(VHIDD/32, NR/64), 256, 0, stream>>>(
        msginb, Wv1T, bv1, nullptr, alpha, Y1b, VINN, 0);

    // MLP GEMM2: K=768, BK=64 dbuf, fused f32 epilogue. 768 blocks.
    k_mgemm_nf<2><<<dim3(HH/32, NR/64), 256, 0, stream>>>(
        Y1b, Wv2T, bv2, nullptr, alpha, out, VHIDD, 0);
}

// Round 16
// 197.093 us; speedup vs baseline: 1.1653x; 1.0312x over previous
//
#include <hip/hip_runtime.h>
#include <math.h>

#define BB   2
#define SS   1024
#define HH   768
#define DD   24
#define HIDD 96
#define VINN 2304   // 3*H
#define VHIDD 768
#define NRR  2048   // BB*SS

typedef __attribute__((ext_vector_type(8))) short short8;
typedef __attribute__((ext_vector_type(4))) float floatx4;

static __device__ inline unsigned short f2bf(float x) {
    unsigned int u = __float_as_uint(x);
    u = (u + 0x7FFFu + ((u >> 16) & 1u)) >> 16;
    return (unsigned short)u;
}
static __device__ inline unsigned int pack2(float a, float b) {
    return (unsigned int)f2bf(a) | ((unsigned int)f2bf(b) << 16);
}

// async global -> LDS, 16 B per lane; LDS dest = wave-uniform base + lane*16
static __device__ inline void gl16(const unsigned short* g, unsigned short* l) {
    __builtin_amdgcn_global_load_lds(
        (const __attribute__((address_space(1))) unsigned int*)g,
        (__attribute__((address_space(3))) unsigned int*)l,
        16, 0, 0);
}

// ---------------- Kernel 0: fused prep --------------------------------------
// blocks 0..63: Z projections (MFMA), packed-bf16 output.
// blocks 64..: f32->bf16 transpose-convert for Wv1T / Wv2T / HiT.
__global__ __launch_bounds__(256) void k_prep(
    const float* __restrict__ Hj, const float* __restrict__ Hi,
    const float* __restrict__ Wpj, const float* __restrict__ Wpi,
    const float* __restrict__ Wv1, const float* __restrict__ Wv2,
    unsigned* __restrict__ Zjp, unsigned* __restrict__ Zip,
    unsigned short* __restrict__ Wv1T, unsigned short* __restrict__ Wv2T,
    unsigned short* __restrict__ HiT)
{
    __shared__ __align__(16) unsigned short sAz[64][72];
    __shared__ __align__(16) unsigned short sBTz[32][72];
    __shared__ float tile[32][33];
    int bid = blockIdx.x;
    int tid = threadIdx.x;

    if (bid < 64) {
        // ---------------- zproj ----------------
        int w = tid >> 6, lane = tid & 63;
        int quad = lane >> 4, col = lane & 15;
        int m0 = bid * 64;
        bool isJ = (m0 < NRR);
        const float* src = isJ ? Hj : Hi;
        const float* Wp  = isJ ? Wpj : Wpi;
        unsigned* Zp     = isJ ? Zjp : Zip;
        int rowbase = isJ ? m0 : (m0 - NRR);

        floatx4 acc[2];
        acc[0] = (floatx4){0.f,0.f,0.f,0.f};
        acc[1] = (floatx4){0.f,0.f,0.f,0.f};

        for (int kb = 0; kb < HH; kb += 64) {
            #pragma unroll
            for (int i = 0; i < 4; ++i) {
                int f4 = tid + i*256;
                int r = f4 >> 4, c4 = f4 & 15;
                float4 v = *(const float4*)(src + (size_t)(rowbase + r)*HH + kb + c4*4);
                uint2 pkt; pkt.x = pack2(v.x, v.y); pkt.y = pack2(v.z, v.w);
                *(uint2*)&sAz[r][c4*4] = pkt;
            }
            {
                const float* wsrc = Wp + (size_t)kb*DD;
                #pragma unroll
                for (int i = 0; i < 6; ++i) {
                    int idx = tid + i*256;
                    int k = idx / DD, n = idx % DD;
                    sBTz[n][k] = f2bf(wsrc[idx]);
                }
            }
            __syncthreads();
            #pragma unroll
            for (int kt = 0; kt < 2; ++kt) {
                short8 av = *(const short8*)&sAz[w*16 + col][kt*32 + quad*8];
                #pragma unroll
                for (int nt = 0; nt < 2; ++nt) {
                    short8 bv = *(const short8*)&sBTz[nt*16 + col][kt*32 + quad*8];
                    acc[nt] = __builtin_amdgcn_mfma_f32_16x16x32_bf16(av, bv, acc[nt], 0, 0, 0);
                }
            }
            __syncthreads();
        }
        #pragma unroll
        for (int nt = 0; nt < 2; ++nt) {
            #pragma unroll
            for (int r = 0; r < 4; ++r) {
                float v = acc[nt][r];
                float vn = __shfl_xor(v, 1, 64);
                int n = nt*16 + col;
                if (!(col & 1) && n < DD) {
                    int m = w*16 + quad*4 + r;
                    Zp[(size_t)(rowbase + m)*12 + (n >> 1)] = pack2(v, vn);
                }
            }
        }
        return;
    }

    // ---------------- tconv segments ----------------
    int b2 = bid - 64;
    const float* in; unsigned short* out; int R, C, r0, c0;
    if (b2 < 1728) {                 // Wv1T: [2304][768] -> [768][2304]
        in = Wv1; out = Wv1T; R = VINN; C = VHIDD;
        c0 = (b2 % 24) * 32; r0 = (b2 / 24) * 32;
    } else if (b2 < 2304) {          // Wv2T: [768][768] -> [768][768]
        int t = b2 - 1728;
        in = Wv2; out = Wv2T; R = VHIDD; C = HH;
        c0 = (t % 24) * 32; r0 = (t / 24) * 32;
    } else {                          // HiT: per batch [1024][768] -> [768][1024]
        int t = b2 - 2304;
        int z = t / 768; t %= 768;
        in = Hi + (size_t)z*SS*HH; out = HiT + (size_t)z*HH*SS;
        R = SS; C = HH;
        c0 = (t % 24) * 32; r0 = (t / 24) * 32;
    }
    int tc = tid & 31, tr = tid >> 5;
    #pragma unroll
    for (int i = 0; i < 4; ++i)
        tile[tr + i*8][tc] = in[(size_t)(r0 + tr + i*8)*C + c0 + tc];
    __syncthreads();
    #pragma unroll
    for (int i = 0; i < 4; ++i)
        out[(size_t)(c0 + tr + i*8)*R + r0 + tc] = f2bf(tile[tc][tr + i*8]);
}

// ---------------- Kernel 2: MFMA logits + softmax -> probs (bf16) ----------
// TC=64 chunks, double-buffered (23 KB LDS).
#define LSTR 72
#define TC 64
__global__ __launch_bounds__(256) void k_attn(
    const unsigned* __restrict__ Zjp, const unsigned* __restrict__ Zip,
    const float* __restrict__ W1, const float* __restrict__ b1,
    const float* __restrict__ W2,
    const float* __restrict__ mask, unsigned short* __restrict__ probs)
{
    int row = blockIdx.x;       // b*S + s
    int b = row >> 10;
    int tid = threadIdx.x;
    int lane = tid & 63, wv = tid >> 6;
    int quad = lane >> 4, col = lane & 15;

    __shared__ __align__(16) unsigned short sAB[2][TC*LSTR]; // B-build flat, then A dbuf
    __shared__ __align__(16) float sLog[SS];
    __shared__ unsigned sZjp[12];
    __shared__ float sW2[HIDD];
    __shared__ float sRed[4];
    unsigned short* sABf = &sAB[0][0];   // flat view (rows 0..127)

    if (tid < 12) sZjp[tid] = Zjp[(size_t)row*12 + tid];
    if (tid < HIDD) sW2[tid] = W2[tid];
    __syncthreads();

    // ---- build B flat (rows h = 0..95, k = 0..63) ----
    if (tid < HIDD) {
        int h = tid;
        float zj[24];
        #pragma unroll
        for (int u = 0; u < 12; ++u) {
            unsigned z = sZjp[u];
            zj[2*u]   = __uint_as_float(z << 16);
            zj[2*u+1] = __uint_as_float(z & 0xffff0000u);
        }
        float tj = b1[h];
        #pragma unroll
        for (int d = 0; d < DD; ++d) tj = fmaf(zj[d], W1[d*HIDD + h], tj);
        unsigned short* rowp = sABf + h*LSTR;
        #pragma unroll
        for (int d = 0; d < DD; ++d)
            rowp[d] = f2bf(fmaf(zj[d], W1[(48+d)*HIDD + h], W1[(24+d)*HIDD + h]));
        #pragma unroll
        for (int d = 0; d < DD; ++d)
            rowp[24+d] = f2bf(W1[(72+d)*HIDD + h]);
        rowp[48] = f2bf(tj);
        #pragma unroll
        for (int k = 49; k < 64; ++k) rowp[k] = 0;
    }
    __syncthreads();

    // hoist B fragments (h-side, MFMA A-operand) + per-lane w2 coeffs
    short8 bfr[6][2];
    #pragma unroll
    for (int nf = 0; nf < 6; ++nf)
        #pragma unroll
        for (int kt = 0; kt < 2; ++kt)
            bfr[nf][kt] = *(const short8*)&sABf[(nf*16 + col)*LSTR + kt*32 + quad*8];
    float4 w2q[6];
    #pragma unroll
    for (int nf = 0; nf < 6; ++nf)
        w2q[nf] = *(const float4*)&sW2[nf*16 + quad*4];
    __syncthreads();   // sAB now reused as A double-buffer

    // constant region k=48..63, both buffers (written once)
    if (tid < 128) {
        int bf = tid >> 6, r = tid & 63;
        unsigned short* rowp = &sAB[bf][r*LSTR];
        uint4 w0; w0.x = 0x3F80u; w0.y = 0; w0.z = 0; w0.w = 0;
        *(uint4*)&rowp[48] = w0;
        uint4 zz; zz.x = 0; zz.y = 0; zz.z = 0; zz.w = 0;
        *(uint4*)&rowp[56] = zz;
    }

    int t_loc = tid >> 2, ss = tid & 3;
    const unsigned* zbase = Zip + (size_t)(b << 10) * 12;

    // hoist Zj unpack (chunk-invariant) for this thread's 3 q-uints
    float zalo[3], zahi[3];
    #pragma unroll
    for (int u = 0; u < 3; ++u) {
        unsigned za = sZjp[3*ss + u];
        zalo[u] = __uint_as_float(za << 16);
        zahi[u] = __uint_as_float(za & 0xffff0000u);
    }

    // A-pack for one chunk (4 threads per t-row; each does 3 q-uints)
    auto pack = [&](int chunk, int bf) {
        int t = chunk*TC + t_loc;
        const unsigned* zr = zbase + (size_t)t*12;
        unsigned short* rowp = &sAB[bf][t_loc*LSTR];
        if (ss < 3) {
            uint4 cp = *(const uint4*)(zr + 4*ss);
            *(uint4*)&rowp[8*ss] = cp;
        }
        unsigned myz[3];
        #pragma unroll
        for (int u = 0; u < 3; ++u) myz[u] = zr[3*ss + u];
        #pragma unroll
        for (int u = 0; u < 3; ++u) {
            unsigned zb = myz[u];
            float blo = __uint_as_float(zb << 16);
            float bhi = __uint_as_float(zb & 0xffff0000u);
            unsigned dlo = __float_as_uint(fabsf(zalo[u] - blo)) + 0x8000u;
            unsigned dhi = __float_as_uint(fabsf(zahi[u] - bhi)) + 0x8000u;
            *(unsigned*)&rowp[24 + 6*ss + 2*u] =
                __builtin_amdgcn_perm(dhi, dlo, 0x07060302u);
        }
    };

    pack(0, 0);
    __syncthreads();

    for (int chunk = 0; chunk < SS/TC; ++chunk) {
        int cur = chunk & 1;
        if (chunk + 1 < SS/TC) pack(chunk + 1, cur ^ 1);

        // MFMA: D[h][t]; per-lane fold over (hf, reg), cross-quad reduce
        int arow = wv*16 + col;
        short8 av0 = *(const short8*)&sAB[cur][arow*LSTR + quad*8];
        short8 av1 = *(const short8*)&sAB[cur][arow*LSTR + 32 + quad*8];
        float s0 = 0.f;
        #pragma unroll
        for (int hf = 0; hf < 6; ++hf) {
            floatx4 a0 = {0.f,0.f,0.f,0.f};
            a0 = __builtin_amdgcn_mfma_f32_16x16x32_bf16(bfr[hf][0], av0, a0, 0, 0, 0);
            a0 = __builtin_amdgcn_mfma_f32_16x16x32_bf16(bfr[hf][1], av1, a0, 0, 0, 0);
            float w2v[4] = {w2q[hf].x, w2q[hf].y, w2q[hf].z, w2q[hf].w};
            #pragma unroll
            for (int r = 0; r < 4; ++r)
                s0 = fmaf(fmaxf(a0[r], 0.f), w2v[r], s0);
        }
        s0 += __shfl_xor(s0, 16, 64);
        s0 += __shfl_xor(s0, 32, 64);
        if (lane < 16)
            sLog[chunk*TC + wv*16 + lane] = s0;
        __syncthreads();
    }

    // ---- softmax ----
    float lv[4];
    #pragma unroll
    for (int i = 0; i < 4; ++i) {
        int t = tid + i*256;
        lv[i] = sLog[t] + (1.0f - mask[(size_t)(b<<10) + t]) * (-3.402823466e+38f);
    }
    float m = fmaxf(fmaxf(lv[0], lv[1]), fmaxf(lv[2], lv[3]));
    #pragma unroll
    for (int off = 32; off; off >>= 1) m = fmaxf(m, __shfl_down(m, off, 64));
    if (lane == 0) sRed[wv] = m;
    __syncthreads();
    float M = fmaxf(fmaxf(sRed[0], sRed[1]), fmaxf(sRed[2], sRed[3]));
    float e[4]; float ssum = 0.f;
    #pragma unroll
    for (int i = 0; i < 4; ++i) { e[i] = expf(lv[i] - M); ssum += e[i]; }
    #pragma unroll
    for (int off = 32; off; off >>= 1) ssum += __shfl_down(ssum, off, 64);
    __syncthreads();
    if (lane == 0) sRed[wv] = ssum;
    __syncthreads();
    float inv = 1.0f / (sRed[0] + sRed[1] + sRed[2] + sRed[3]);
    #pragma unroll
    for (int i = 0; i < 4; ++i)
        probs[(size_t)row*SS + tid + i*256] = f2bf(e[i] * inv);
}

// ---------------- Kernel 3: no-split GEMM, 64Mx32N, fused epilogue ---------
// MODE 0: msgin builder (ctx | hj | ctx*hj, bf16)
// MODE 1: Y1 = bf16(relu(acc + bias))
// MODE 2: out = f32(alpha*(acc + bias))
template<int MODE>
__global__ __launch_bounds__(256) void k_mgemm_nf(
    const unsigned short* __restrict__ A,
    const unsigned short* __restrict__ BT,
    const float* __restrict__ bias,
    const float* __restrict__ Hj,
    const float* __restrict__ alpha_p,
    void* __restrict__ Cout,
    int K, int bt_bstride)
{
    __shared__ __align__(16) unsigned short sA[64*64];
    __shared__ __align__(16) unsigned short sB[32*64];
    int tid = threadIdx.x;
    int w = tid >> 6, lane = tid & 63;
    int quad = lane >> 4, col = lane & 15;

    int n0 = blockIdx.x * 32, m0 = blockIdx.y * 64;
    int nk = K >> 6;
    const unsigned short* Bb = BT + (size_t)(m0 >> 10) * bt_bstride;

    int srow = lane >> 3;
    int skc  = (lane & 7) * 8;

    floatx4 acc[2];
    acc[0] = (floatx4){0.f,0.f,0.f,0.f};
    acc[1] = (floatx4){0.f,0.f,0.f,0.f};

    for (int kb = 0; kb < nk; ++kb) {
        int kofs = kb*64;
        gl16(A  + (size_t)(m0 + w*16     + srow)*K + kofs + skc, &sA[(w*16)*64]);
        gl16(A  + (size_t)(m0 + w*16 + 8 + srow)*K + kofs + skc, &sA[(w*16 + 8)*64]);
        gl16(Bb + (size_t)(n0 + w*8      + srow)*K + kofs + skc, &sB[(w*8)*64]);
        __syncthreads();
        #pragma unroll
        for (int kt = 0; kt < 2; ++kt) {
            short8 av = *(const short8*)&sA[(w*16 + col)*64 + kt*32 + quad*8];
            #pragma unroll
            for (int nf = 0; nf < 2; ++nf) {
                short8 bv = *(const short8*)&sB[(nf*16 + col)*64 + kt*32 + quad*8];
                acc[nf] = __builtin_amdgcn_mfma_f32_16x16x32_bf16(av, bv, acc[nf], 0, 0, 0);
            }
        }
        __syncthreads();
    }

    float alpha = (MODE == 2) ? alpha_p[0] : 1.0f;
    #pragma unroll
    for (int nf = 0; nf < 2; ++nf) {
        int n = n0 + nf*16 + col;
        #pragma unroll
        for (int r = 0; r < 4; ++r) {
            int m = w*16 + quad*4 + r;
            size_t g = (size_t)(m0 + m);
            float v = acc[nf][r];
            if (MODE == 0) {
                float hj = Hj[g*HH + n];
                unsigned short* msgin = (unsigned short*)Cout;
                msgin[g*VINN + n]        = f2bf(v);
                msgin[g*VINN + HH + n]   = f2bf(hj);
                msgin[g*VINN + 2*HH + n] = f2bf(v*hj);
            } else if (MODE == 1) {
                ((unsigned short*)Cout)[g*VHIDD + n] =
                    f2bf(fmaxf(v + bias[n], 0.f));
            } else {
                ((float*)Cout)[g*HH + n] = alpha*(v + bias[n]);
            }
        }
    }
}

extern "C" void kernel_launch(void* const* d_in, const int* in_sizes, int n_in,
                              void* d_out, int out_size, void* d_ws, size_t ws_size,
                              hipStream_t stream)
{
    const float* Hj   = (const float*)d_in[0];
    const float* Hi   = (const float*)d_in[1];
    const float* mask = (const float*)d_in[2];
    const float* Wpj  = (const float*)d_in[3];
    const float* Wpi  = (const float*)d_in[4];
    const float* W1   = (const float*)d_in[5];
    const float* b1   = (const float*)d_in[6];
    const float* W2   = (const float*)d_in[7];
    const float* Wv1  = (const float*)d_in[9];
    const float* bv1  = (const float*)d_in[10];
    const float* Wv2  = (const float*)d_in[11];
    const float* bv2  = (const float*)d_in[12];
    const float* alpha = (const float*)d_in[13];
    float* out = (float*)d_out;

    const int NR = NRR;                   // 2048
    char* p = (char*)d_ws;
    auto alloc = [&](size_t bytes) {
        char* r = p; p += (bytes + 255) & ~(size_t)255; return r;
    };
    unsigned* Zjp          = (unsigned*)alloc((size_t)NR*12*4);
    unsigned* Zip          = (unsigned*)alloc((size_t)NR*12*4);
    unsigned short* probsb = (unsigned short*)alloc((size_t)NR*SS*2);
    unsigned short* HiT    = (unsigned short*)alloc((size_t)BB*HH*SS*2);
    unsigned short* Wv1T   = (unsigned short*)alloc((size_t)VHIDD*VINN*2);
    unsigned short* Wv2T   = (unsigned short*)alloc((size_t)HH*VHIDD*2);
    unsigned short* msginb = (unsigned short*)alloc((size_t)NR*VINN*2);
    unsigned short* Y1b    = (unsigned short*)alloc((size_t)NR*VHIDD*2);

    // prep: 64 zproj blocks + 1728 (Wv1T) + 576 (Wv2T) + 1536 (HiT) tconv blocks
    k_prep<<<64 + 1728 + 576 + 1536, 256, 0, stream>>>(
        Hj, Hi, Wpj, Wpi, Wv1, Wv2, Zjp, Zip, Wv1T, Wv2T, HiT);

    k_attn<<<NR, 256, 0, stream>>>(Zjp, Zip, W1, b1, W2, mask, probsb);

    // ctx GEMM: M=2048 (batch via bt stride), N=768, K=1024, no split,
    // fused msgin epilogue. 24 x 32 = 768 blocks.
    k_mgemm_nf<0><<<dim3(HH/32, NR/64), 256, 0, stream>>>(
        probsb, HiT, nullptr, Hj, alpha, msginb, SS, HH*SS);

    // MLP GEMM1: K=2304, no split, fused bias+relu epilogue. 768 blocks.
    k_mgemm_nf<1><<<dim3(VHIDD/32, NR/64), 256, 0, stream>>>(
        msginb, Wv1T, bv1, nullptr, alpha, Y1b, VINN, 0);

    // MLP GEMM2: K=768, no split, fused f32 epilogue. 768 blocks.
    k_mgemm_nf<2><<<dim3(HH/32, NR/64), 256, 0, stream>>>(
        Y1b, Wv2T, bv2, nullptr, alpha, out, VHIDD, 0);
}

// Round 17
// 195.035 us; speedup vs baseline: 1.1776x; 1.0106x over previous
//
#include <hip/hip_runtime.h>
#include <math.h>

#define BB   2
#define SS   1024
#define HH   768
#define DD   24
#define HIDD 96
#define VINN 2304   // 3*H
#define VHIDD 768
#define NRR  2048   // BB*SS

typedef __attribute__((ext_vector_type(8))) short short8;
typedef __attribute__((ext_vector_type(4))) float floatx4;

static __device__ inline unsigned short f2bf(float x) {
    unsigned int u = __float_as_uint(x);
    u = (u + 0x7FFFu + ((u >> 16) & 1u)) >> 16;
    return (unsigned short)u;
}
static __device__ inline unsigned int pack2(float a, float b) {
    return (unsigned int)f2bf(a) | ((unsigned int)f2bf(b) << 16);
}

// async global -> LDS, 16 B per lane; LDS dest = wave-uniform base + lane*16
static __device__ inline void gl16(const unsigned short* g, unsigned short* l) {
    __builtin_amdgcn_global_load_lds(
        (const __attribute__((address_space(1))) unsigned int*)g,
        (__attribute__((address_space(3))) unsigned int*)l,
        16, 0, 0);
}

// ---------------- Kernel 0: Z projections via MFMA (64 blocks) -------------
__global__ __launch_bounds__(256) void k_zproj(
    const float* __restrict__ Hj, const float* __restrict__ Hi,
    const float* __restrict__ Wpj, const float* __restrict__ Wpi,
    unsigned* __restrict__ Zjp, unsigned* __restrict__ Zip)
{
    __shared__ __align__(16) unsigned short sAz[64][72];
    __shared__ __align__(16) unsigned short sBTz[32][72];
    int tid = threadIdx.x;
    int w = tid >> 6, lane = tid & 63;
    int quad = lane >> 4, col = lane & 15;
    int m0 = blockIdx.x * 64;
    bool isJ = (m0 < NRR);
    const float* src = isJ ? Hj : Hi;
    const float* Wp  = isJ ? Wpj : Wpi;
    unsigned* Zp     = isJ ? Zjp : Zip;
    int rowbase = isJ ? m0 : (m0 - NRR);

    floatx4 acc[2];
    acc[0] = (floatx4){0.f,0.f,0.f,0.f};
    acc[1] = (floatx4){0.f,0.f,0.f,0.f};

    for (int kb = 0; kb < HH; kb += 64) {
        #pragma unroll
        for (int i = 0; i < 4; ++i) {
            int f4 = tid + i*256;
            int r = f4 >> 4, c4 = f4 & 15;
            float4 v = *(const float4*)(src + (size_t)(rowbase + r)*HH + kb + c4*4);
            uint2 pkt; pkt.x = pack2(v.x, v.y); pkt.y = pack2(v.z, v.w);
            *(uint2*)&sAz[r][c4*4] = pkt;
        }
        {
            const float* wsrc = Wp + (size_t)kb*DD;
            #pragma unroll
            for (int i = 0; i < 6; ++i) {
                int idx = tid + i*256;
                int k = idx / DD, n = idx % DD;
                sBTz[n][k] = f2bf(wsrc[idx]);
            }
        }
        __syncthreads();
        #pragma unroll
        for (int kt = 0; kt < 2; ++kt) {
            short8 av = *(const short8*)&sAz[w*16 + col][kt*32 + quad*8];
            #pragma unroll
            for (int nt = 0; nt < 2; ++nt) {
                short8 bv = *(const short8*)&sBTz[nt*16 + col][kt*32 + quad*8];
                acc[nt] = __builtin_amdgcn_mfma_f32_16x16x32_bf16(av, bv, acc[nt], 0, 0, 0);
            }
        }
        __syncthreads();
    }
    #pragma unroll
    for (int nt = 0; nt < 2; ++nt) {
        #pragma unroll
        for (int r = 0; r < 4; ++r) {
            float v = acc[nt][r];
            float vn = __shfl_xor(v, 1, 64);
            int n = nt*16 + col;
            if (!(col & 1) && n < DD) {
                int m = w*16 + quad*4 + r;
                Zp[(size_t)(rowbase + m)*12 + (n >> 1)] = pack2(v, vn);
            }
        }
    }
}

// ---------------- Kernel 2: MFMA logits + softmax -> probs (bf16) ----------
// blocks 0..2047: attention rows (TC=64 chunks, double-buffered, 23 KB LDS).
// blocks 2048.. : f32->bf16 transpose-convert (Wv1T / Wv2T / HiT), overlaid
//                 on the attn LDS — outputs consumed only by later kernels.
#define LSTR 72
#define TC 64
__global__ __launch_bounds__(256) void k_attn(
    const unsigned* __restrict__ Zjp, const unsigned* __restrict__ Zip,
    const float* __restrict__ W1, const float* __restrict__ b1,
    const float* __restrict__ W2,
    const float* __restrict__ mask, unsigned short* __restrict__ probs,
    const float* __restrict__ Hi, const float* __restrict__ Wv1,
    const float* __restrict__ Wv2,
    unsigned short* __restrict__ Wv1T, unsigned short* __restrict__ Wv2T,
    unsigned short* __restrict__ HiT)
{
    int tid = threadIdx.x;
    __shared__ __align__(16) unsigned short sAB[2][TC*LSTR]; // B-build flat, then A dbuf
    __shared__ __align__(16) float sLog[SS];
    __shared__ unsigned sZjp[12];
    __shared__ float sW2[HIDD];
    __shared__ float sRed[4];
    unsigned short* sABf = &sAB[0][0];   // flat view (rows 0..127)

    if (blockIdx.x >= NRR) {
        // ---------------- tconv segment ----------------
        int b2 = blockIdx.x - NRR;
        const float* in; unsigned short* out; int R, C, r0, c0;
        if (b2 < 1728) {                 // Wv1T: [2304][768] -> [768][2304]
            in = Wv1; out = Wv1T; R = VINN; C = VHIDD;
            c0 = (b2 % 24) * 32; r0 = (b2 / 24) * 32;
        } else if (b2 < 2304) {          // Wv2T: [768][768] -> [768][768]
            int t = b2 - 1728;
            in = Wv2; out = Wv2T; R = VHIDD; C = HH;
            c0 = (t % 24) * 32; r0 = (t / 24) * 32;
        } else {                          // HiT: per batch [1024][768] -> [768][1024]
            int t = b2 - 2304;
            int z = t / 768; t %= 768;
            in = Hi + (size_t)z*SS*HH; out = HiT + (size_t)z*HH*SS;
            R = SS; C = HH;
            c0 = (t % 24) * 32; r0 = (t / 24) * 32;
        }
        float* tile = (float*)sABf;      // 32x33 floats = 4224 B, fits in sAB
        int tc = tid & 31, tr = tid >> 5;
        #pragma unroll
        for (int i = 0; i < 4; ++i)
            tile[(tr + i*8)*33 + tc] = in[(size_t)(r0 + tr + i*8)*C + c0 + tc];
        __syncthreads();
        #pragma unroll
        for (int i = 0; i < 4; ++i)
            out[(size_t)(c0 + tr + i*8)*R + r0 + tc] = f2bf(tile[tc*33 + tr + i*8]);
        return;
    }

    // ---------------- attention row ----------------
    int row = blockIdx.x;       // b*S + s
    int b = row >> 10;
    int lane = tid & 63, wv = tid >> 6;
    int quad = lane >> 4, col = lane & 15;

    if (tid < 12) sZjp[tid] = Zjp[(size_t)row*12 + tid];
    if (tid < HIDD) sW2[tid] = W2[tid];
    __syncthreads();

    // ---- build B flat (rows h = 0..95, k = 0..63) ----
    if (tid < HIDD) {
        int h = tid;
        float zj[24];
        #pragma unroll
        for (int u = 0; u < 12; ++u) {
            unsigned z = sZjp[u];
            zj[2*u]   = __uint_as_float(z << 16);
            zj[2*u+1] = __uint_as_float(z & 0xffff0000u);
        }
        float tj = b1[h];
        #pragma unroll
        for (int d = 0; d < DD; ++d) tj = fmaf(zj[d], W1[d*HIDD + h], tj);
        unsigned short* rowp = sABf + h*LSTR;
        #pragma unroll
        for (int d = 0; d < DD; ++d)
            rowp[d] = f2bf(fmaf(zj[d], W1[(48+d)*HIDD + h], W1[(24+d)*HIDD + h]));
        #pragma unroll
        for (int d = 0; d < DD; ++d)
            rowp[24+d] = f2bf(W1[(72+d)*HIDD + h]);
        rowp[48] = f2bf(tj);
        #pragma unroll
        for (int k = 49; k < 64; ++k) rowp[k] = 0;
    }
    __syncthreads();

    // hoist B fragments (h-side, MFMA A-operand) + per-lane w2 coeffs
    short8 bfr[6][2];
    #pragma unroll
    for (int nf = 0; nf < 6; ++nf)
        #pragma unroll
        for (int kt = 0; kt < 2; ++kt)
            bfr[nf][kt] = *(const short8*)&sABf[(nf*16 + col)*LSTR + kt*32 + quad*8];
    float4 w2q[6];
    #pragma unroll
    for (int nf = 0; nf < 6; ++nf)
        w2q[nf] = *(const float4*)&sW2[nf*16 + quad*4];
    __syncthreads();   // sAB now reused as A double-buffer

    // constant region k=48..63, both buffers (written once)
    if (tid < 128) {
        int bf = tid >> 6, r = tid & 63;
        unsigned short* rowp = &sAB[bf][r*LSTR];
        uint4 w0; w0.x = 0x3F80u; w0.y = 0; w0.z = 0; w0.w = 0;
        *(uint4*)&rowp[48] = w0;
        uint4 zz; zz.x = 0; zz.y = 0; zz.z = 0; zz.w = 0;
        *(uint4*)&rowp[56] = zz;
    }

    int t_loc = tid >> 2, ss = tid & 3;
    const unsigned* zbase = Zip + (size_t)(b << 10) * 12;

    // hoist Zj unpack (chunk-invariant) for this thread's 3 q-uints
    float zalo[3], zahi[3];
    #pragma unroll
    for (int u = 0; u < 3; ++u) {
        unsigned za = sZjp[3*ss + u];
        zalo[u] = __uint_as_float(za << 16);
        zahi[u] = __uint_as_float(za & 0xffff0000u);
    }

    // A-pack for one chunk (4 threads per t-row; each does 3 q-uints)
    auto pack = [&](int chunk, int bf) {
        int t = chunk*TC + t_loc;
        const unsigned* zr = zbase + (size_t)t*12;
        unsigned short* rowp = &sAB[bf][t_loc*LSTR];
        if (ss < 3) {
            uint4 cp = *(const uint4*)(zr + 4*ss);
            *(uint4*)&rowp[8*ss] = cp;
        }
        unsigned myz[3];
        #pragma unroll
        for (int u = 0; u < 3; ++u) myz[u] = zr[3*ss + u];
        #pragma unroll
        for (int u = 0; u < 3; ++u) {
            unsigned zb = myz[u];
            float blo = __uint_as_float(zb << 16);
            float bhi = __uint_as_float(zb & 0xffff0000u);
            unsigned dlo = __float_as_uint(fabsf(zalo[u] - blo)) + 0x8000u;
            unsigned dhi = __float_as_uint(fabsf(zahi[u] - bhi)) + 0x8000u;
            *(unsigned*)&rowp[24 + 6*ss + 2*u] =
                __builtin_amdgcn_perm(dhi, dlo, 0x07060302u);
        }
    };

    pack(0, 0);
    __syncthreads();

    for (int chunk = 0; chunk < SS/TC; ++chunk) {
        int cur = chunk & 1;
        if (chunk + 1 < SS/TC) pack(chunk + 1, cur ^ 1);

        // MFMA: D[h][t]; per-lane fold over (hf, reg), cross-quad reduce
        int arow = wv*16 + col;
        short8 av0 = *(const short8*)&sAB[cur][arow*LSTR + quad*8];
        short8 av1 = *(const short8*)&sAB[cur][arow*LSTR + 32 + quad*8];
        float s0 = 0.f;
        #pragma unroll
        for (int hf = 0; hf < 6; ++hf) {
            floatx4 a0 = {0.f,0.f,0.f,0.f};
            a0 = __builtin_amdgcn_mfma_f32_16x16x32_bf16(bfr[hf][0], av0, a0, 0, 0, 0);
            a0 = __builtin_amdgcn_mfma_f32_16x16x32_bf16(bfr[hf][1], av1, a0, 0, 0, 0);
            float w2v[4] = {w2q[hf].x, w2q[hf].y, w2q[hf].z, w2q[hf].w};
            #pragma unroll
            for (int r = 0; r < 4; ++r)
                s0 = fmaf(fmaxf(a0[r], 0.f), w2v[r], s0);
        }
        s0 += __shfl_xor(s0, 16, 64);
        s0 += __shfl_xor(s0, 32, 64);
        if (lane < 16)
            sLog[chunk*TC + wv*16 + lane] = s0;
        __syncthreads();
    }

    // ---- softmax ----
    float lv[4];
    #pragma unroll
    for (int i = 0; i < 4; ++i) {
        int t = tid + i*256;
        lv[i] = sLog[t] + (1.0f - mask[(size_t)(b<<10) + t]) * (-3.402823466e+38f);
    }
    float m = fmaxf(fmaxf(lv[0], lv[1]), fmaxf(lv[2], lv[3]));
    #pragma unroll
    for (int off = 32; off; off >>= 1) m = fmaxf(m, __shfl_down(m, off, 64));
    if (lane == 0) sRed[wv] = m;
    __syncthreads();
    float M = fmaxf(fmaxf(sRed[0], sRed[1]), fmaxf(sRed[2], sRed[3]));
    float e[4]; float ssum = 0.f;
    #pragma unroll
    for (int i = 0; i < 4; ++i) { e[i] = expf(lv[i] - M); ssum += e[i]; }
    #pragma unroll
    for (int off = 32; off; off >>= 1) ssum += __shfl_down(ssum, off, 64);
    __syncthreads();
    if (lane == 0) sRed[wv] = ssum;
    __syncthreads();
    float inv = 1.0f / (sRed[0] + sRed[1] + sRed[2] + sRed[3]);
    #pragma unroll
    for (int i = 0; i < 4; ++i)
        probs[(size_t)row*SS + tid + i*256] = f2bf(e[i] * inv);
}

// ---------------- Kernel 3: no-split GEMM, 64Mx32N, fused epilogue ---------
// MODE 0: msgin builder (ctx | hj | ctx*hj, bf16)
// MODE 1: Y1 = bf16(relu(acc + bias))
// MODE 2: out = f32(alpha*(acc + bias))
template<int MODE>
__global__ __launch_bounds__(256) void k_mgemm_nf(
    const unsigned short* __restrict__ A,
    const unsigned short* __restrict__ BT,
    const float* __restrict__ bias,
    const float* __restrict__ Hj,
    const float* __restrict__ alpha_p,
    void* __restrict__ Cout,
    int K, int bt_bstride)
{
    __shared__ __align__(16) unsigned short sA[64*64];
    __shared__ __align__(16) unsigned short sB[32*64];
    int tid = threadIdx.x;
    int w = tid >> 6, lane = tid & 63;
    int quad = lane >> 4, col = lane & 15;

    int n0 = blockIdx.x * 32, m0 = blockIdx.y * 64;
    int nk = K >> 6;
    const unsigned short* Bb = BT + (size_t)(m0 >> 10) * bt_bstride;

    int srow = lane >> 3;
    int skc  = (lane & 7) * 8;

    floatx4 acc[2];
    acc[0] = (floatx4){0.f,0.f,0.f,0.f};
    acc[1] = (floatx4){0.f,0.f,0.f,0.f};

    for (int kb = 0; kb < nk; ++kb) {
        int kofs = kb*64;
        gl16(A  + (size_t)(m0 + w*16     + srow)*K + kofs + skc, &sA[(w*16)*64]);
        gl16(A  + (size_t)(m0 + w*16 + 8 + srow)*K + kofs + skc, &sA[(w*16 + 8)*64]);
        gl16(Bb + (size_t)(n0 + w*8      + srow)*K + kofs + skc, &sB[(w*8)*64]);
        __syncthreads();
        #pragma unroll
        for (int kt = 0; kt < 2; ++kt) {
            short8 av = *(const short8*)&sA[(w*16 + col)*64 + kt*32 + quad*8];
            #pragma unroll
            for (int nf = 0; nf < 2; ++nf) {
                short8 bv = *(const short8*)&sB[(nf*16 + col)*64 + kt*32 + quad*8];
                acc[nf] = __builtin_amdgcn_mfma_f32_16x16x32_bf16(av, bv, acc[nf], 0, 0, 0);
            }
        }
        __syncthreads();
    }

    float alpha = (MODE == 2) ? alpha_p[0] : 1.0f;
    #pragma unroll
    for (int nf = 0; nf < 2; ++nf) {
        int n = n0 + nf*16 + col;
        #pragma unroll
        for (int r = 0; r < 4; ++r) {
            int m = w*16 + quad*4 + r;
            size_t g = (size_t)(m0 + m);
            float v = acc[nf][r];
            if (MODE == 0) {
                float hj = Hj[g*HH + n];
                unsigned short* msgin = (unsigned short*)Cout;
                msgin[g*VINN + n]        = f2bf(v);
                msgin[g*VINN + HH + n]   = f2bf(hj);
                msgin[g*VINN + 2*HH + n] = f2bf(v*hj);
            } else if (MODE == 1) {
                ((unsigned short*)Cout)[g*VHIDD + n] =
                    f2bf(fmaxf(v + bias[n], 0.f));
            } else {
                ((float*)Cout)[g*HH + n] = alpha*(v + bias[n]);
            }
        }
    }
}

extern "C" void kernel_launch(void* const* d_in, const int* in_sizes, int n_in,
                              void* d_out, int out_size, void* d_ws, size_t ws_size,
                              hipStream_t stream)
{
    const float* Hj   = (const float*)d_in[0];
    const float* Hi   = (const float*)d_in[1];
    const float* mask = (const float*)d_in[2];
    const float* Wpj  = (const float*)d_in[3];
    const float* Wpi  = (const float*)d_in[4];
    const float* W1   = (const float*)d_in[5];
    const float* b1   = (const float*)d_in[6];
    const float* W2   = (const float*)d_in[7];
    const float* Wv1  = (const float*)d_in[9];
    const float* bv1  = (const float*)d_in[10];
    const float* Wv2  = (const float*)d_in[11];
    const float* bv2  = (const float*)d_in[12];
    const float* alpha = (const float*)d_in[13];
    float* out = (float*)d_out;

    const int NR = NRR;                   // 2048
    char* p = (char*)d_ws;
    auto alloc = [&](size_t bytes) {
        char* r = p; p += (bytes + 255) & ~(size_t)255; return r;
    };
    unsigned* Zjp          = (unsigned*)alloc((size_t)NR*12*4);
    unsigned* Zip          = (unsigned*)alloc((size_t)NR*12*4);
    unsigned short* probsb = (unsigned short*)alloc((size_t)NR*SS*2);
    unsigned short* HiT    = (unsigned short*)alloc((size_t)BB*HH*SS*2);
    unsigned short* Wv1T   = (unsigned short*)alloc((size_t)VHIDD*VINN*2);
    unsigned short* Wv2T   = (unsigned short*)alloc((size_t)HH*VHIDD*2);
    unsigned short* msginb = (unsigned short*)alloc((size_t)NR*VINN*2);
    unsigned short* Y1b    = (unsigned short*)alloc((size_t)NR*VHIDD*2);

    // zproj only: 64 blocks (k_attn depends solely on this)
    k_zproj<<<2*NR/64, 256, 0, stream>>>(Hj, Hi, Wpj, Wpi, Zjp, Zip);

    // attn (2048 blocks) + tconv (3840 blocks) packed in one dispatch:
    // tconv outputs (HiT/Wv1T/Wv2T) are first consumed by the GEMMs below.
    k_attn<<<NR + 1728 + 576 + 1536, 256, 0, stream>>>(
        Zjp, Zip, W1, b1, W2, mask, probsb,
        Hi, Wv1, Wv2, Wv1T, Wv2T, HiT);

    // ctx GEMM: M=2048 (batch via bt stride), N=768, K=1024, no split,
    // fused msgin epilogue. 24 x 32 = 768 blocks.
    k_mgemm_nf<0><<<dim3(HH/32, NR/64), 256, 0, stream>>>(
        probsb, HiT, nullptr, Hj, alpha, msginb, SS, HH*SS);

    // MLP GEMM1: K=2304, no split, fused bias+relu epilogue. 768 blocks.
    k_mgemm_nf<1><<<dim3(VHIDD/32, NR/64), 256, 0, stream>>>(
        msginb, Wv1T, bv1, nullptr, alpha, Y1b, VINN, 0);

    // MLP GEMM2: K=768, no split, fused f32 epilogue. 768 blocks.
    k_mgemm_nf<2><<<dim3(HH/32, NR/64), 256, 0, stream>>>(
        Y1b, Wv2T, bv2, nullptr, alpha, out, VHIDD, 0);
}